// Round 6
// baseline (120.195 us; speedup 1.0000x reference)
//
#include <hip/hip_runtime.h>
#include <math.h>

#define NEL   4096
#define NT    512            // block size: 8 waves
#define HALF  256            // threads per array half in consumer
#define EPT   16             // sorted elements per half-thread
#define CPT   8              // original indices per thread (both arrays)
#define NPROD 256            // producer blocks (2 arr x 8 i-chunks x 16 j-segs)
#define JLEN  256            // j-segment length
#define MAGICZ 0x13579BDFu   // no repeated-byte pattern -> poison-proof
#define DONE_W 8192          // ws word index of done counter (inside zeroed rgn)
#define ZFLG_W 8193          // ws word index of zero-done flag

// wave-synchronous LDS fence (lanes lockstep; drains own wave's ds ops)
#define WSYNC() asm volatile("s_waitcnt lgkmcnt(0)" ::: "memory")

// ---------------------------------------------------------------------------
// division-free single-boundary pool merge of [lo,mid) and [mid,hi).
// invariant: block [a,b] has C[a] == C[b] == b-a+1.
// mean compares done as cross-multiplication (lens > 0, products < 2^45).
// ---------------------------------------------------------------------------
__device__ inline void pav_merge(double* P, int* C, const int lo, const int mid,
                                 const int hi) {
  const int llen = C[mid - 1];
  int cs = mid - llen;
  const int rlen = C[mid];
  int ce = mid + rlen - 1;
  const double Pmid = P[mid];
  double Pcs = P[cs], Pce1 = P[ce + 1];
  // mL <= mR  <=>  (Pmid-Pcs)*rlen <= (Pce1-Pmid)*llen
  if ((Pmid - Pcs) * (double)rlen <= (Pce1 - Pmid) * (double)llen) {
    bool changed = true;
    while (changed) {
      changed = false;
      while (cs > lo) {                  // absorb left block if mean <= mu
        const int l2 = C[cs - 1];
        const double Pl = P[cs - l2];
        if ((Pcs - Pl) * (double)(ce - cs + 1) <= (Pce1 - Pcs) * (double)l2) {
          cs -= l2; Pcs = Pl; changed = true;
        } else break;
      }
      while (ce < hi - 1) {              // absorb right block if mean >= mu
        const int l2 = C[ce + 1];
        const double Pr = P[ce + 1 + l2];
        if ((Pr - Pce1) * (double)(ce - cs + 1) >= (Pce1 - Pcs) * (double)l2) {
          ce += l2; Pce1 = Pr; changed = true;
        } else break;
      }
    }
    const int len = ce - cs + 1;
    C[cs] = len;
    C[ce] = len;
  }
}

// ---------------------------------------------------------------------------
// ONE kernel, 257 blocks x 512 threads (129 KB LDS -> 1 block/CU).
// block 0 (consumer): zero counts+done -> release zflag -> poll done counter
//                     -> PAV + loss.
// blocks 1..256 (producers): compute 256-j partial count (overlaps zeroing)
//   -> single-poller wait on zflag -> atomicAdd into counts -> fence ->
//   one atomicAdd on done counter -> exit.
// ws words: counts[0..8191] | done[8192] | zflag[8193]
// ---------------------------------------------------------------------------
__global__ __launch_bounds__(NT, 1)
void spearman_kernel(const float* __restrict__ pred,
                     const float* __restrict__ target,
                     unsigned int* __restrict__ ws,
                     float* __restrict__ loss_out) {
  __shared__ float  s_val[2][NEL];      // sorted values; later sorted ranks
  __shared__ double s_P[2][NEL + 1];    // prefix sums of z
  __shared__ int    s_cnt[2][NEL];      // block stamps -> bstart list
  __shared__ double s_wsum[2][HALF / 64];
  __shared__ int    s_nb[2];
  __shared__ double s_red[NT / 64][5];

  const int tid  = threadIdx.x;
  const int lane = tid & 63;
  const int wid  = tid >> 6;

  if (blockIdx.x != 0) {
    // =================== PRODUCER =========================================
    const int pid = blockIdx.x - 1;          // 0..255
    const int parr = pid >> 7;               // 0/1
    const int rem  = pid & 127;
    const int ic   = rem >> 4;               // 0..7  (i-chunk of 512)
    const int js   = rem & 15;               // 0..15 (j-seg of 256)
    const float* __restrict__ x = parr ? target : pred;
    const int i     = ic * NT + tid;
    const int jbase = js * JLEN;

    float* jv = s_val[0];                    // reuse LDS
    if (tid < JLEN) jv[tid] = x[jbase + tid];
    const float xi = x[i];
    __syncthreads();

    unsigned int c = 0;
    const float4* jv4 = (const float4*)jv;
#pragma unroll 8
    for (int t4 = 0; t4 < JLEN / 4; t4++) {
      const float4 v = jv4[t4];              // wave-uniform broadcast
      const int j = jbase + 4 * t4;
      c += (v.x > xi || (v.x == xi && j + 0 < i)) ? 1u : 0u;
      c += (v.y > xi || (v.y == xi && j + 1 < i)) ? 1u : 0u;
      c += (v.z > xi || (v.z == xi && j + 2 < i)) ? 1u : 0u;
      c += (v.w > xi || (v.w == xi && j + 3 < i)) ? 1u : 0u;
    }
    // single-poller relaxed spin on zflag, acquire once on exit
    if (tid == 0) {
      while (__hip_atomic_load(&ws[ZFLG_W], __ATOMIC_RELAXED,
                               __HIP_MEMORY_SCOPE_AGENT) != MAGICZ)
        __builtin_amdgcn_s_sleep(2);
      (void)__hip_atomic_load(&ws[ZFLG_W], __ATOMIC_ACQUIRE,
                              __HIP_MEMORY_SCOPE_AGENT);
    }
    __syncthreads();
    atomicAdd(&ws[parr * NEL + i], c);       // device-scope, distinct addrs
    __threadfence();                         // per-thread: own add visible
    __syncthreads();
    if (tid == 0)
      __hip_atomic_fetch_add(&ws[DONE_W], 1u, __ATOMIC_RELEASE,
                             __HIP_MEMORY_SCOPE_AGENT);
    return;
  }

  // ===================== CONSUMER (block 0) ===============================
  // prefetch own values while zeroing (orig indices 8*tid .. 8*tid+7)
  const float4 xp0 = ((const float4*)pred)[2 * tid];
  const float4 xp1 = ((const float4*)pred)[2 * tid + 1];
  const float4 xt0 = ((const float4*)target)[2 * tid];
  const float4 xt1 = ((const float4*)target)[2 * tid + 1];
  {
    const int4 z = make_int4(0, 0, 0, 0);
    int4* w4 = (int4*)ws;                    // counts = 2048 int4
    w4[tid] = z; w4[tid + 512] = z; w4[tid + 1024] = z; w4[tid + 1536] = z;
    if (tid == 0) ws[DONE_W] = 0u;
  }
  __syncthreads();                                   // B1
  if (tid == 0) {
    __threadfence();                         // zeros visible agent-wide
    __hip_atomic_store(&ws[ZFLG_W], MAGICZ, __ATOMIC_RELEASE,
                       __HIP_MEMORY_SCOPE_AGENT);
    unsigned int v;
    do {                                     // single-address relaxed poll
      __builtin_amdgcn_s_sleep(2);
      v = __hip_atomic_load(&ws[DONE_W], __ATOMIC_RELAXED,
                            __HIP_MEMORY_SCOPE_AGENT);
    } while (v != NPROD);
    (void)__hip_atomic_load(&ws[DONE_W], __ATOMIC_ACQUIRE,
                            __HIP_MEMORY_SCOPE_AGENT);  // CU cache inval
  }
  __syncthreads();                                   // B2

  // ---- read final counts (= sorted positions); scatter values ------------
  int rp[CPT], rt[CPT];
  {
    const int4 a0 = ((const int4*)ws)[2 * tid];
    const int4 a1 = ((const int4*)ws)[2 * tid + 1];
    const int4 b0_ = ((const int4*)ws)[NEL / 4 + 2 * tid];
    const int4 b1_ = ((const int4*)ws)[NEL / 4 + 2 * tid + 1];
    rp[0] = a0.x; rp[1] = a0.y; rp[2] = a0.z; rp[3] = a0.w;
    rp[4] = a1.x; rp[5] = a1.y; rp[6] = a1.z; rp[7] = a1.w;
    rt[0] = b0_.x; rt[1] = b0_.y; rt[2] = b0_.z; rt[3] = b0_.w;
    rt[4] = b1_.x; rt[5] = b1_.y; rt[6] = b1_.z; rt[7] = b1_.w;
    s_val[0][rp[0]] = xp0.x; s_val[0][rp[1]] = xp0.y;
    s_val[0][rp[2]] = xp0.z; s_val[0][rp[3]] = xp0.w;
    s_val[0][rp[4]] = xp1.x; s_val[0][rp[5]] = xp1.y;
    s_val[0][rp[6]] = xp1.z; s_val[0][rp[7]] = xp1.w;
    s_val[1][rt[0]] = xt0.x; s_val[1][rt[1]] = xt0.y;
    s_val[1][rt[2]] = xt0.z; s_val[1][rt[3]] = xt0.w;
    s_val[1][rt[4]] = xt1.x; s_val[1][rt[5]] = xt1.y;
    s_val[1][rt[6]] = xt1.z; s_val[1][rt[7]] = xt1.w;
  }
  __syncthreads();                                   // B3

  // ---- sorted-range ownership --------------------------------------------
  const int arr = tid >> 8;            // 0: pred, 1: target
  const int tA  = tid & (HALF - 1);
  const int wA  = tA >> 6;             // wave within half, 0..3
  const int b0  = tA * EPT;
  double* P = s_P[arr];
  int*    C = s_cnt[arr];

  // ---- register prefix of z_p = s_p - (NEL - p) over own 16 elements -----
  double c[EPT];
  {
    double acc = 0.0;
#pragma unroll
    for (int e = 0; e < EPT; e++) {
      const int p = b0 + e;
      acc += (double)s_val[arr][p] - (double)(NEL - p);
      c[e] = acc;
    }
  }
  const double tot = c[EPT - 1];
  double sc = tot;
#pragma unroll
  for (int d = 1; d < 64; d <<= 1) {
    const double o = __shfl_up(sc, d, 64);
    if (lane >= d) sc += o;
  }
  if (lane == 63) s_wsum[arr][wA] = sc;
  __syncthreads();                                   // B4
  double wexcl = 0.0;
#pragma unroll
  for (int w = 0; w < HALF / 64; w++)
    wexcl += (w < wA) ? s_wsum[arr][w] : 0.0;
  const double excl = wexcl + (sc - tot);            // == P[b0]
#pragma unroll
  for (int e = 0; e < EPT; e++) P[b0 + 1 + e] = excl + c[e];
  if (lane == 0) P[b0] = excl;         // covers P[0] = 0 via tA==0

  // ---- serial left-to-right PAV on own 16 elements: no sync, div-free ----
  C[b0] = 1;
  for (int p = b0 + 1; p < b0 + EPT; p++) {
    int cs = p;
    const double Pe = P[p + 1];        // own-written
    while (cs > b0) {
      const int l2 = C[cs - 1];
      const int lb = cs - l2;
      const double Pcs = P[cs];
      const double Plb = (lb == b0) ? excl : P[lb];
      if ((Pcs - Plb) * (double)(p - cs + 1) <= (Pe - Pcs) * (double)l2)
        cs = lb;
      else break;
    }
    C[cs] = p - cs + 1;
    C[p]  = p - cs + 1;
  }
  WSYNC();

  // ---- within-wave levels m = 16..512 (wave span 1024), wave-sync --------
  const int wbase = wA * 1024;
#pragma unroll
  for (int m = EPT; m <= 512; m <<= 1) {
    const int nm = 1024 / (2 * m);
    if (lane < nm) {
      const int lo = wbase + lane * 2 * m;
      pav_merge(P, C, lo, lo + m, lo + 2 * m);
    }
    WSYNC();
  }
  __syncthreads();                                   // B5

  // ---- cross-wave levels m = 1024, 2048 + walk: wave 0 of each half ------
  if (wA == 0) {
#pragma unroll
    for (int m = 1024; m <= 2048; m <<= 1) {
      const int nm = NEL / (2 * m);
      if (lane < nm) {
        const int lo = lane * 2 * m;
        pav_merge(P, C, lo, lo + m, lo + 2 * m);
      }
      WSYNC();
    }
    if (lane == 0) {                   // walk block list -> bstart (aliased;
      int s = 0, b = 0;                //  reads lead writes)
      while (s < NEL) {
        const int cc = C[s];
        C[b] = s;
        b++;
        s += cc;
      }
      s_nb[arr] = b;
    }
  }
  __syncthreads();                                   // B6

  // ---- rank at own sorted positions, in place ----------------------------
  const int nb = s_nb[arr];
#pragma unroll
  for (int e = 0; e < EPT; e++) {
    const int p = b0 + e;
    int lo = 0, hi = nb - 1;
    while (lo < hi) {
      const int md = (lo + hi + 1) >> 1;
      if (C[md] <= p) lo = md; else hi = md - 1;
    }
    const int st = C[lo];
    const int en = (lo + 1 < nb) ? C[lo + 1] : NEL;
    const double v = (P[en] - P[st]) / (double)(en - st);
    s_val[arr][p] = (float)((double)s_val[arr][p] - v);
  }
  __syncthreads();                                   // B7

  // ---- Pearson loss: gather both rank vectors via rp/rt ------------------
  double Sp = 0.0, Sq = 0.0, Spp = 0.0, Sqq = 0.0, Spq = 0.0;
#pragma unroll
  for (int e = 0; e < CPT; e++) {
    const double p = (double)s_val[0][rp[e]];
    const double q = (double)s_val[1][rt[e]];
    Sp += p; Sq += q; Spp += p * p; Sqq += q * q; Spq += p * q;
  }
#pragma unroll
  for (int d = 32; d > 0; d >>= 1) {
    Sp  += __shfl_down(Sp,  d, 64);
    Sq  += __shfl_down(Sq,  d, 64);
    Spp += __shfl_down(Spp, d, 64);
    Sqq += __shfl_down(Sqq, d, 64);
    Spq += __shfl_down(Spq, d, 64);
  }
  if (lane == 0) {
    s_red[wid][0] = Sp;  s_red[wid][1] = Sq;  s_red[wid][2] = Spp;
    s_red[wid][3] = Sqq; s_red[wid][4] = Spq;
  }
  __syncthreads();                                   // B8
  if (tid == 0) {
    double a0 = 0, a1 = 0, a2 = 0, a3 = 0, a4 = 0;
    for (int w = 0; w < NT / 64; w++) {
      a0 += s_red[w][0]; a1 += s_red[w][1]; a2 += s_red[w][2];
      a3 += s_red[w][3]; a4 += s_red[w][4];
    }
    const double n  = (double)NEL;
    const double mp = a0 / n, mq = a1 / n;
    const double cov = a4 - n * mp * mq;
    const double vp  = a2 - n * mp * mp;
    const double vq  = a3 - n * mq * mq;
    loss_out[0] = (float)(1.0 - cov / sqrt(vp * vq));
  }
}

// ---------------------------------------------------------------------------
extern "C" void kernel_launch(void* const* d_in, const int* in_sizes, int n_in,
                              void* d_out, int out_size, void* d_ws, size_t ws_size,
                              hipStream_t stream) {
  const float* pred   = (const float*)d_in[0];
  const float* target = (const float*)d_in[1];
  unsigned int* ws = (unsigned int*)d_ws;  // counts | done | zflag (~33 KB)
  float* out = (float*)d_out;

  hipLaunchKernelGGL(spearman_kernel, dim3(NPROD + 1), dim3(NT), 0, stream,
                     pred, target, ws, out);
}

// Round 7
// 80.520 us; speedup vs baseline: 1.4927x; 1.4927x over previous
//
#include <hip/hip_runtime.h>
#include <math.h>

#define NEL   4096
#define NT    1024           // consumer block: 16 waves
#define HALF  512            // threads per array half (sorted-range ownership)
#define EPT   8              // sorted elements per half-thread
#define CPT   4              // original indices per thread (both arrays)
#define CB    256            // count_kernel block size / j-tile

// bank-conflict-breaking padded index: one pad slot every 8 elements.
// lane-stride becomes 9 elements -> spreads across all 32 banks.
#define IX(p) ((p) + ((p) >> 3))

// wave-synchronous LDS fence (lanes lockstep; drains own wave's ds ops)
#define WSYNC() asm volatile("s_waitcnt lgkmcnt(0)" ::: "memory")

// ---------------------------------------------------------------------------
// Kernel A (R2-proven shape): brute-force stable descending ranks.
// grid (16,16,2), 256 threads. counts must be pre-zeroed (memset node).
// ---------------------------------------------------------------------------
__global__ __launch_bounds__(CB)
void count_kernel(const float* __restrict__ pred,
                  const float* __restrict__ target,
                  unsigned int* __restrict__ counts) {
  __shared__ float jv[CB];
  const int arr = blockIdx.z;
  const float* __restrict__ x = arr ? target : pred;
  const int i     = blockIdx.x * CB + threadIdx.x;
  const int jbase = blockIdx.y * CB;

  jv[threadIdx.x] = x[jbase + threadIdx.x];
  const float xi = x[i];
  __syncthreads();

  const float4* jv4 = (const float4*)jv;
  unsigned int c = 0;
#pragma unroll 4
  for (int t4 = 0; t4 < CB / 4; t4++) {
    const float4 v = jv4[t4];            // wave-uniform LDS broadcast
    const int j = jbase + 4 * t4;
    c += (v.x > xi || (v.x == xi && j + 0 < i)) ? 1u : 0u;
    c += (v.y > xi || (v.y == xi && j + 1 < i)) ? 1u : 0u;
    c += (v.z > xi || (v.z == xi && j + 2 < i)) ? 1u : 0u;
    c += (v.w > xi || (v.w == xi && j + 3 < i)) ? 1u : 0u;
  }
  atomicAdd(&counts[arr * NEL + i], c);  // 16 adds/address, device scope
}

// ---------------------------------------------------------------------------
// division-free single-boundary pool merge of [lo,mid) and [mid,hi).
// invariant: block [a,b] has C[a] == C[b] == b-a+1. P accessed via IX().
// ---------------------------------------------------------------------------
__device__ inline void pav_merge(double* P, int* C, const int lo, const int mid,
                                 const int hi) {
  const int llen = C[mid - 1];
  int cs = mid - llen;
  const int rlen = C[mid];
  int ce = mid + rlen - 1;
  const double Pmid = P[IX(mid)];
  double Pcs = P[IX(cs)], Pce1 = P[IX(ce + 1)];
  // mL <= mR  <=>  (Pmid-Pcs)*rlen <= (Pce1-Pmid)*llen   (lens > 0)
  if ((Pmid - Pcs) * (double)rlen <= (Pce1 - Pmid) * (double)llen) {
    bool changed = true;
    while (changed) {
      changed = false;
      while (cs > lo) {                  // absorb left block if mean <= mu
        const int l2 = C[cs - 1];
        const double Pl = P[IX(cs - l2)];
        if ((Pcs - Pl) * (double)(ce - cs + 1) <= (Pce1 - Pcs) * (double)l2) {
          cs -= l2; Pcs = Pl; changed = true;
        } else break;
      }
      while (ce < hi - 1) {              // absorb right block if mean >= mu
        const int l2 = C[ce + 1];
        const double Pr = P[IX(ce + 1 + l2)];
        if ((Pr - Pce1) * (double)(ce - cs + 1) >= (Pce1 - Pcs) * (double)l2) {
          ce += l2; Pce1 = Pr; changed = true;
        } else break;
      }
    }
    const int len = ce - cs + 1;
    C[cs] = len;
    C[ce] = len;
  }
}

// ---------------------------------------------------------------------------
// Kernel B (one block, 1024 threads): scatter -> prefix -> register-minimax
// local PAV -> wave-sync merges -> cross-wave merges -> ranks -> loss.
// LDS ~= 144 KB (s_P/s_val padded via IX to break bank conflicts).
// ---------------------------------------------------------------------------
__global__ __launch_bounds__(NT)
void pav_loss_kernel(const float* __restrict__ pred,
                     const float* __restrict__ target,
                     const unsigned int* __restrict__ counts,
                     float* __restrict__ loss_out) {
  __shared__ float  s_val[2][IX(NEL - 1) + 2];   // padded; values then ranks
  __shared__ double s_P[2][IX(NEL) + 1];         // padded prefix sums of z
  __shared__ int    s_cnt[2][NEL];               // block stamps -> bstart
  __shared__ double s_wsum[2][HALF / 64];
  __shared__ int    s_nb[2];
  __shared__ double s_red[NT / 64][5];

  const int tid  = threadIdx.x;
  const int lane = tid & 63;
  const int wid  = tid >> 6;

  // ---- phase A: read counts (= sorted positions) + values, scatter -------
  int rp[CPT], rt[CPT];
  {
    const uint4 a = ((const uint4*)counts)[tid];
    const uint4 b = ((const uint4*)counts)[NEL / 4 + tid];
    rp[0] = (int)a.x; rp[1] = (int)a.y; rp[2] = (int)a.z; rp[3] = (int)a.w;
    rt[0] = (int)b.x; rt[1] = (int)b.y; rt[2] = (int)b.z; rt[3] = (int)b.w;
    const float4 xp = ((const float4*)pred)[tid];
    const float4 xt = ((const float4*)target)[tid];
    s_val[0][IX(rp[0])] = xp.x; s_val[0][IX(rp[1])] = xp.y;
    s_val[0][IX(rp[2])] = xp.z; s_val[0][IX(rp[3])] = xp.w;
    s_val[1][IX(rt[0])] = xt.x; s_val[1][IX(rt[1])] = xt.y;
    s_val[1][IX(rt[2])] = xt.z; s_val[1][IX(rt[3])] = xt.w;
  }
  __syncthreads();                                   // B1

  // ---- sorted-range ownership --------------------------------------------
  const int arr = tid >> 9;            // 0: pred, 1: target
  const int tA  = tid & (HALF - 1);
  const int wA  = tA >> 6;             // wave within half, 0..7
  const int b0  = tA * EPT;
  double* P = s_P[arr];
  int*    C = s_cnt[arr];

  // ---- register prefix of z_p = s_p - (NEL - p) over own 8 elements ------
  double c[EPT];
  {
    double acc = 0.0;
#pragma unroll
    for (int e = 0; e < EPT; e++) {
      const int p = b0 + e;
      acc += (double)s_val[arr][IX(p)] - (double)(NEL - p);
      c[e] = acc;
    }
  }
  const double tot = c[EPT - 1];
  double sc = tot;                     // wave-inclusive scan of thread totals
#pragma unroll
  for (int d = 1; d < 64; d <<= 1) {
    const double o = __shfl_up(sc, d, 64);
    if (lane >= d) sc += o;
  }
  if (lane == 63) s_wsum[arr][wA] = sc;
  __syncthreads();                                   // B2
  double wexcl = 0.0;
#pragma unroll
  for (int w = 0; w < HALF / 64; w++)
    wexcl += (w < wA) ? s_wsum[arr][w] : 0.0;
  const double excl = wexcl + (sc - tot);            // == P[b0]
#pragma unroll
  for (int e = 0; e < EPT; e++) P[IX(b0 + 1 + e)] = excl + c[e];
  if (lane == 0) P[IX(b0)] = excl;     // wave-span base (benign 1-ulp race
                                       //  with prev lane63; proven R4/R6)

  // ---- local PAV on own 8 elements: register minimax, division-free ------
  // v_p = min_{j<=p} max_{k>=p} mean(j..k); means kept as (num,den) pairs.
  // sum(j..k) = c[k] - (j ? c[j-1] : 0)
  double nmx[EPT]; int dmx[EPT];       // running max-over-k pair per j
  double vn[EPT];  int vd[EPT];        // v pair per p
  {
    // peel p = 7 (k = 7 candidates init the max table)
#pragma unroll
    for (int j = 0; j < EPT; j++) {
      nmx[j] = c[7] - (j ? c[j - 1] : 0.0);
      dmx[j] = EPT - j;
    }
    double mn = nmx[0]; int md = dmx[0];
#pragma unroll
    for (int j = 1; j < EPT; j++)
      if (nmx[j] * (double)md < mn * (double)dmx[j]) { mn = nmx[j]; md = dmx[j]; }
    vn[7] = mn; vd[7] = md;
#pragma unroll
    for (int p = EPT - 2; p >= 0; p--) {
#pragma unroll
      for (int j = 0; j < EPT - 1; j++) {
        if (j <= p) {
          const double cnum = c[p] - (j ? c[j - 1] : 0.0);
          const int cden = p - j + 1;
          if (cnum * (double)dmx[j] > nmx[j] * (double)cden) {
            nmx[j] = cnum; dmx[j] = cden;
          }
        }
      }
      double mn2 = nmx[0]; int md2 = dmx[0];
#pragma unroll
      for (int j = 1; j < EPT - 1; j++) {
        if (j <= p) {
          if (nmx[j] * (double)md2 < mn2 * (double)dmx[j]) {
            mn2 = nmx[j]; md2 = dmx[j];
          }
        }
      }
      vn[p] = mn2; vd[p] = md2;
    }
  }
  // stamps: runs of identical (vn,vd) pairs = local PAV blocks
  {
    int runstart = b0;
#pragma unroll
    for (int e = 1; e < EPT; e++) {
      const bool neq = (vd[e] != vd[e - 1]) ||
                       (__double_as_longlong(vn[e]) !=
                        __double_as_longlong(vn[e - 1]));
      if (neq) {
        const int len = b0 + e - runstart;
        C[runstart] = len;
        C[b0 + e - 1] = len;
        runstart = b0 + e;
      }
    }
    const int len = b0 + EPT - runstart;
    C[runstart] = len;
    C[b0 + EPT - 1] = len;
  }
  WSYNC();   // own wave's P + stamps visible wave-wide (lockstep)

  // ---- within-wave levels m = 8..256 (wave span 512), wave-synchronous ---
  const int wbase = wA * 512;
#pragma unroll
  for (int m = EPT; m <= 256; m <<= 1) {
    const int nm = 512 / (2 * m);
    if (lane < nm) {
      const int lo = wbase + lane * 2 * m;
      pav_merge(P, C, lo, lo + m, lo + 2 * m);
    }
    WSYNC();
  }
  __syncthreads();                                   // B3

  // ---- cross-wave levels m = 512..2048 + walk: wave 0 of each half -------
  if (wA == 0) {
#pragma unroll
    for (int m = 512; m <= 2048; m <<= 1) {
      const int nm = NEL / (2 * m);
      if (lane < nm) {
        const int lo = lane * 2 * m;
        pav_merge(P, C, lo, lo + m, lo + 2 * m);
      }
      WSYNC();
    }
    if (lane == 0) {                   // walk block list -> bstart (aliased;
      int s = 0, b = 0;                //  reads lead writes)
      while (s < NEL) {
        const int cc = C[s];
        C[b] = s;
        b++;
        s += cc;
      }
      s_nb[arr] = b;
    }
  }
  __syncthreads();                                   // B4

  // ---- rank at own sorted positions, in place ----------------------------
  const int nb = s_nb[arr];
#pragma unroll
  for (int e = 0; e < EPT; e++) {
    const int p = b0 + e;
    int lo = 0, hi = nb - 1;
    while (lo < hi) {
      const int md = (lo + hi + 1) >> 1;
      if (C[md] <= p) lo = md; else hi = md - 1;
    }
    const int st = C[lo];
    const int en = (lo + 1 < nb) ? C[lo + 1] : NEL;
    const double v = (P[IX(en)] - P[IX(st)]) / (double)(en - st);
    s_val[arr][IX(p)] = (float)((double)s_val[arr][IX(p)] - v);
  }
  __syncthreads();                                   // B5

  // ---- Pearson loss: gather both rank vectors via rp/rt ------------------
  double Sp = 0.0, Sq = 0.0, Spp = 0.0, Sqq = 0.0, Spq = 0.0;
#pragma unroll
  for (int e = 0; e < CPT; e++) {
    const double p = (double)s_val[0][IX(rp[e])];
    const double q = (double)s_val[1][IX(rt[e])];
    Sp += p; Sq += q; Spp += p * p; Sqq += q * q; Spq += p * q;
  }
#pragma unroll
  for (int d = 32; d > 0; d >>= 1) {
    Sp  += __shfl_down(Sp,  d, 64);
    Sq  += __shfl_down(Sq,  d, 64);
    Spp += __shfl_down(Spp, d, 64);
    Sqq += __shfl_down(Sqq, d, 64);
    Spq += __shfl_down(Spq, d, 64);
  }
  if (lane == 0) {
    s_red[wid][0] = Sp;  s_red[wid][1] = Sq;  s_red[wid][2] = Spp;
    s_red[wid][3] = Sqq; s_red[wid][4] = Spq;
  }
  __syncthreads();                                   // B6
  if (tid == 0) {
    double a0 = 0, a1 = 0, a2 = 0, a3 = 0, a4 = 0;
    for (int w = 0; w < NT / 64; w++) {
      a0 += s_red[w][0]; a1 += s_red[w][1]; a2 += s_red[w][2];
      a3 += s_red[w][3]; a4 += s_red[w][4];
    }
    const double n  = (double)NEL;
    const double mp = a0 / n, mq = a1 / n;
    const double cov = a4 - n * mp * mq;
    const double vp  = a2 - n * mp * mp;
    const double vq  = a3 - n * mq * mq;
    loss_out[0] = (float)(1.0 - cov / sqrt(vp * vq));
  }
}

// ---------------------------------------------------------------------------
extern "C" void kernel_launch(void* const* d_in, const int* in_sizes, int n_in,
                              void* d_out, int out_size, void* d_ws, size_t ws_size,
                              hipStream_t stream) {
  const float* pred   = (const float*)d_in[0];
  const float* target = (const float*)d_in[1];
  unsigned int* counts = (unsigned int*)d_ws;   // 2 * NEL u32 = 32 KB
  float* out = (float*)d_out;

  hipMemsetAsync(counts, 0, 2 * NEL * sizeof(unsigned int), stream);
  hipLaunchKernelGGL(count_kernel, dim3(NEL / CB, NEL / CB, 2), dim3(CB), 0,
                     stream, pred, target, counts);
  hipLaunchKernelGGL(pav_loss_kernel, dim3(1), dim3(NT), 0, stream,
                     pred, target, counts, out);
}